// Round 1
// baseline (233.522 us; speedup 1.0000x reference)
//
#include <hip/hip_runtime.h>

#define N_BINS 15
#define NSPREAD 32           // global-atomic contention spreading
#define SEG (3 * N_BINS)     // cnt | conf | acc per replica

__device__ __forceinline__ unsigned umax_(unsigned a, unsigned b) { return a > b ? a : b; }

// 16 lanes cooperate per row; each lane loads one float4 (wave reads 1KiB contiguous).
// Argmax packed key: conf in [1/64,1] -> fbits in [0x3C800000,0x3F800000];
// key = ((fbits-OFF)<<6) | (63-idx): unsigned max == (max val, first index).
__global__ __launch_bounds__(256) void ece_partial_kernel(
    const float* __restrict__ sm, const int* __restrict__ labels,
    float* __restrict__ g, int n)
{
    __shared__ float s_cnt[N_BINS];
    __shared__ float s_conf[N_BINS];
    __shared__ float s_acc[N_BINS];
    const int tid = threadIdx.x;
    if (tid < N_BINS) { s_cnt[tid] = 0.f; s_conf[tid] = 0.f; s_acc[tid] = 0.f; }
    __syncthreads();

    const unsigned OFF = 0x3C800000u;
    const int sub = tid & 15;                       // position within row
    const long long rows_per_grid = (long long)gridDim.x * 16;

    for (long long row = (long long)blockIdx.x * 16 + (tid >> 4);
         row < n; row += rows_per_grid)
    {
        const float4 v = *reinterpret_cast<const float4*>(sm + (row << 6) + (sub << 2));
        const int base = sub << 2;
        unsigned k0 = ((umax_(__float_as_uint(v.x), OFF) - OFF) << 6) | (unsigned)(63 - base);
        unsigned k1 = ((umax_(__float_as_uint(v.y), OFF) - OFF) << 6) | (unsigned)(62 - base);
        unsigned k2 = ((umax_(__float_as_uint(v.z), OFF) - OFF) << 6) | (unsigned)(61 - base);
        unsigned k3 = ((umax_(__float_as_uint(v.w), OFF) - OFF) << 6) | (unsigned)(60 - base);
        unsigned key = umax_(umax_(k0, k1), umax_(k2, k3));

        #pragma unroll
        for (int off = 1; off < 16; off <<= 1) {
            unsigned ok = (unsigned)__shfl_xor((int)key, off);
            key = umax_(key, ok);
        }

        if (sub == 0) {
            const float m = __uint_as_float((key >> 6) + OFF);   // confidence
            const int pred = 63 - (int)(key & 63u);              // argmax (first occurrence)
            const float acc = (pred == labels[row]) ? 1.0f : 0.0f;
            // bid = #{j in 1..15 : j/15 < m}  (== searchsorted(bounds, m, 'left') - 1)
            int bid = 0;
            #pragma unroll
            for (int j = 1; j <= N_BINS; ++j)
                bid += ((float)j / 15.0f < m) ? 1 : 0;
            if (bid > N_BINS - 1) bid = N_BINS - 1;  // safety (m <= 1.0 anyway)
            atomicAdd(&s_cnt[bid], 1.0f);
            atomicAdd(&s_conf[bid], m);
            atomicAdd(&s_acc[bid], acc);
        }
    }

    __syncthreads();
    if (tid < N_BINS) {
        float* gp = g + (blockIdx.x & (NSPREAD - 1)) * SEG;
        atomicAdd(&gp[tid],            s_cnt[tid]);
        atomicAdd(&gp[N_BINS + tid],   s_conf[tid]);
        atomicAdd(&gp[2*N_BINS + tid], s_acc[tid]);
    }
}

__global__ void ece_final_kernel(const float* __restrict__ g, float* __restrict__ out, int n)
{
    __shared__ float s[SEG];
    const int tid = threadIdx.x;
    if (tid < SEG) {
        float v = 0.f;
        #pragma unroll
        for (int r = 0; r < NSPREAD; ++r) v += g[r * SEG + tid];
        s[tid] = v;
    }
    __syncthreads();
    if (tid == 0) {
        float total = 0.f;
        #pragma unroll
        for (int i = 0; i < N_BINS; ++i) {
            const float c = s[i];
            if (c > 0.f) {
                const float d = fmaxf(c, 1.f);
                total += fabsf(s[N_BINS + i] / d - s[2*N_BINS + i] / d) * (c / (float)n);
            }
        }
        out[0] = total;
    }
}

extern "C" void kernel_launch(void* const* d_in, const int* in_sizes, int n_in,
                              void* d_out, int out_size, void* d_ws, size_t ws_size,
                              hipStream_t stream) {
    const float* sm     = (const float*)d_in[0];
    const int*   labels = (const int*)d_in[1];
    float* out = (float*)d_out;
    float* g   = (float*)d_ws;
    const int n = in_sizes[1];   // number of rows (labels count)

    hipMemsetAsync(g, 0, NSPREAD * SEG * sizeof(float), stream);

    const int grid = 2048;       // 2048 blocks x 16 rows/iter -> 128 grid-stride iters
    ece_partial_kernel<<<grid, 256, 0, stream>>>(sm, labels, g, n);
    ece_final_kernel<<<1, 64, 0, stream>>>(g, out, n);
}

// Round 2
// 219.187 us; speedup vs baseline: 1.0654x; 1.0654x over previous
//
#include <hip/hip_runtime.h>

#define N_BINS 15
#define NREP 8               // LDS histogram replicas (de-contention)
#define NSPREAD 32           // global-atomic contention spreading
#define SEG (3 * N_BINS)     // cnt | conf | acc per replica
#define HWORDS (NREP * SEG)  // 360 floats of LDS histogram

__device__ __forceinline__ unsigned umax_(unsigned a, unsigned b) { return a > b ? a : b; }

// Argmax packed key: conf in [1/64,1] -> fbits in [0x3C800000,0x3F800000];
// key = ((fbits-OFF)<<6) | (63-idx): unsigned max == (max val, first index).
#define OFFBITS 0x3C800000u

__device__ __forceinline__ unsigned row_key(const float4 v, const int sub) {
    const int base = sub << 2;
    unsigned k0 = ((umax_(__float_as_uint(v.x), OFFBITS) - OFFBITS) << 6) | (unsigned)(63 - base);
    unsigned k1 = ((umax_(__float_as_uint(v.y), OFFBITS) - OFFBITS) << 6) | (unsigned)(62 - base);
    unsigned k2 = ((umax_(__float_as_uint(v.z), OFFBITS) - OFFBITS) << 6) | (unsigned)(61 - base);
    unsigned k3 = ((umax_(__float_as_uint(v.w), OFFBITS) - OFFBITS) << 6) | (unsigned)(60 - base);
    return umax_(umax_(k0, k1), umax_(k2, k3));
}

// After a 16-lane xor-butterfly all lanes hold the group max.
// Lanes sub 0/1/2 each commit one value (cnt/conf/acc) -> one LDS atomic instr per row.
__device__ __forceinline__ void commit(float* hrep, unsigned key, int sub, int lab) {
    if (sub < 3) {
        const float m = __uint_as_float((key >> 6) + OFFBITS);   // confidence
        int bid = 0;
        #pragma unroll
        for (int j = 1; j <= N_BINS; ++j)
            bid += ((float)j / 15.0f < m) ? 1 : 0;               // searchsorted-left - 1
        if (bid > N_BINS - 1) bid = N_BINS - 1;
        float val;
        if (sub == 0)      val = 1.0f;
        else if (sub == 1) val = m;
        else {
            const int pred = 63 - (int)(key & 63u);              // first-occurrence argmax
            val = (pred == lab) ? 1.0f : 0.0f;
        }
        atomicAdd(&hrep[sub * N_BINS + bid], val);
    }
}

__global__ __launch_bounds__(256) void ece_partial_kernel(
    const float* __restrict__ sm, const int* __restrict__ labels,
    float* __restrict__ g, int n)
{
    __shared__ float s_hist[HWORDS];
    const int tid = threadIdx.x;
    for (int i = tid; i < HWORDS; i += 256) s_hist[i] = 0.f;
    __syncthreads();

    const int sub = tid & 15;                         // position within row
    float* hrep = s_hist + ((tid >> 4) & (NREP - 1)) * SEG;
    const long long step = (long long)gridDim.x * 16;
    long long row = (long long)blockIdx.x * 16 + (tid >> 4);

    // 2x unrolled: both float4 loads (and label loads) in flight before use.
    for (; row + step < n; row += 2 * step) {
        const float4 v0 = *reinterpret_cast<const float4*>(sm + (row << 6) + (sub << 2));
        const float4 v1 = *reinterpret_cast<const float4*>(sm + ((row + step) << 6) + (sub << 2));
        int lab0 = 0, lab1 = 0;
        if (sub == 2) { lab0 = labels[row]; lab1 = labels[row + step]; }

        unsigned key0 = row_key(v0, sub);
        unsigned key1 = row_key(v1, sub);
        #pragma unroll
        for (int off = 1; off < 16; off <<= 1) {
            key0 = umax_(key0, (unsigned)__shfl_xor((int)key0, off));
            key1 = umax_(key1, (unsigned)__shfl_xor((int)key1, off));
        }
        commit(hrep, key0, sub, lab0);
        commit(hrep, key1, sub, lab1);
    }
    if (row < n) {
        const float4 v0 = *reinterpret_cast<const float4*>(sm + (row << 6) + (sub << 2));
        int lab0 = 0;
        if (sub == 2) lab0 = labels[row];
        unsigned key0 = row_key(v0, sub);
        #pragma unroll
        for (int off = 1; off < 16; off <<= 1)
            key0 = umax_(key0, (unsigned)__shfl_xor((int)key0, off));
        commit(hrep, key0, sub, lab0);
    }

    __syncthreads();
    // reduce replicas, then spread global atomics across NSPREAD copies
    if (tid < SEG) {
        float v = 0.f;
        #pragma unroll
        for (int r = 0; r < NREP; ++r) v += s_hist[r * SEG + tid];
        atomicAdd(&g[(blockIdx.x & (NSPREAD - 1)) * SEG + tid], v);
    }
}

__global__ void ece_final_kernel(const float* __restrict__ g, float* __restrict__ out, int n)
{
    __shared__ float s[SEG];
    const int tid = threadIdx.x;
    if (tid < SEG) {
        float v = 0.f;
        #pragma unroll
        for (int r = 0; r < NSPREAD; ++r) v += g[r * SEG + tid];
        s[tid] = v;
    }
    __syncthreads();
    if (tid == 0) {
        float total = 0.f;
        #pragma unroll
        for (int i = 0; i < N_BINS; ++i) {
            const float c = s[i];
            if (c > 0.f) {
                const float d = fmaxf(c, 1.f);
                total += fabsf(s[N_BINS + i] / d - s[2*N_BINS + i] / d) * (c / (float)n);
            }
        }
        out[0] = total;
    }
}

extern "C" void kernel_launch(void* const* d_in, const int* in_sizes, int n_in,
                              void* d_out, int out_size, void* d_ws, size_t ws_size,
                              hipStream_t stream) {
    const float* sm     = (const float*)d_in[0];
    const int*   labels = (const int*)d_in[1];
    float* out = (float*)d_out;
    float* g   = (float*)d_ws;
    const int n = in_sizes[1];   // number of rows (labels count)

    hipMemsetAsync(g, 0, NSPREAD * SEG * sizeof(float), stream);

    const int grid = 2048;       // 2048 blocks x 16 rows/iter; 2x-unrolled grid-stride
    ece_partial_kernel<<<grid, 256, 0, stream>>>(sm, labels, g, n);
    ece_final_kernel<<<1, 64, 0, stream>>>(g, out, n);
}

// Round 3
// 199.229 us; speedup vs baseline: 1.1721x; 1.1002x over previous
//
#include <hip/hip_runtime.h>

#define N_BINS 15
#define NREP 8               // LDS histogram replicas (de-contention)
#define NSPREAD 32           // global-atomic contention spreading
#define SEG (3 * N_BINS)     // cnt | conf | acc per replica
#define HWORDS (NREP * SEG)  // 360 floats of LDS histogram

__device__ __forceinline__ unsigned umax_(unsigned a, unsigned b) { return a > b ? a : b; }

// Argmax packed key: conf in [1/64,1] -> fbits in [0x3C800000,0x3F800000];
// key = ((fbits-OFF)<<6) | (63-idx): unsigned max == (max val, first index).
#define OFFBITS 0x3C800000u

__device__ __forceinline__ unsigned row_key(const float4 v, const int sub) {
    const int base = sub << 2;
    unsigned k0 = ((umax_(__float_as_uint(v.x), OFFBITS) - OFFBITS) << 6) | (unsigned)(63 - base);
    unsigned k1 = ((umax_(__float_as_uint(v.y), OFFBITS) - OFFBITS) << 6) | (unsigned)(62 - base);
    unsigned k2 = ((umax_(__float_as_uint(v.z), OFFBITS) - OFFBITS) << 6) | (unsigned)(61 - base);
    unsigned k3 = ((umax_(__float_as_uint(v.w), OFFBITS) - OFFBITS) << 6) | (unsigned)(60 - base);
    return umax_(umax_(k0, k1), umax_(k2, k3));
}

__device__ __forceinline__ int bin_of(float conf) {
    int bid = 0;
    #pragma unroll
    for (int j = 1; j <= N_BINS; ++j)
        bid += ((float)j / 15.0f < conf) ? 1 : 0;   // searchsorted-left - 1
    return bid > N_BINS - 1 ? N_BINS - 1 : bid;
}

// single-row commit (tail path): lanes sub 0/1/2 each push one metric
__device__ __forceinline__ void commit1(float* hrep, unsigned key, int sub, int lab) {
    if (sub < 3) {
        const float m = __uint_as_float((key >> 6) + OFFBITS);
        const int bid = bin_of(m);
        float val;
        if (sub == 0)      val = 1.0f;
        else if (sub == 1) val = m;
        else {
            const int pred = 63 - (int)(key & 63u);
            val = (pred == lab) ? 1.0f : 0.0f;
        }
        atomicAdd(&hrep[sub * N_BINS + bid], val);
    }
}

__global__ __launch_bounds__(256) void ece_partial_kernel(
    const float* __restrict__ sm, const int* __restrict__ labels,
    float* __restrict__ g, int n)
{
    __shared__ float s_hist[HWORDS];
    const int tid = threadIdx.x;
    for (int i = tid; i < HWORDS; i += 256) s_hist[i] = 0.f;
    __syncthreads();

    const int sub = tid & 15;          // lane within 16-lane row group
    const int grp = tid >> 4;          // group 0..15 within block
    float* hrep = s_hist + (grp & (NREP - 1)) * SEG;
    const int col = sub << 2;

    const long long R = (long long)gridDim.x * 64;     // rows per grid stage
    const long long nfull = ((long long)n / R) * R;

    // Main loop: each group owns 4 consecutive rows/stage; block sweeps 64
    // consecutive rows -> device access is one sequential sweep. All 4 float4
    // loads + label load issue before any use (4x MLP per lane).
    for (long long rb = (long long)blockIdx.x * 64 + ((long long)grp << 2);
         rb < nfull; rb += R)
    {
        const float4 v0 = *reinterpret_cast<const float4*>(sm + (rb << 6) + col);
        const float4 v1 = *reinterpret_cast<const float4*>(sm + ((rb + 1) << 6) + col);
        const float4 v2 = *reinterpret_cast<const float4*>(sm + ((rb + 2) << 6) + col);
        const float4 v3 = *reinterpret_cast<const float4*>(sm + ((rb + 3) << 6) + col);
        int lab = 0;
        if ((unsigned)(sub - 8) < 4u) lab = labels[rb + (sub & 3)];  // acc-lanes: 16B/group coalesced

        unsigned k0 = row_key(v0, sub);
        unsigned k1 = row_key(v1, sub);
        unsigned k2 = row_key(v2, sub);
        unsigned k3 = row_key(v3, sub);
        #pragma unroll
        for (int off = 1; off < 16; off <<= 1) {       // 4 interleaved butterflies
            k0 = umax_(k0, (unsigned)__shfl_xor((int)k0, off));
            k1 = umax_(k1, (unsigned)__shfl_xor((int)k1, off));
            k2 = umax_(k2, (unsigned)__shfl_xor((int)k2, off));
            k3 = umax_(k3, (unsigned)__shfl_xor((int)k3, off));
        }

        // One atomic instruction commits 4 rows x 3 metrics: lane sub=4*m+r
        // owns (row r, metric m). cndmask-selected key (no dynamic reg index).
        if (sub < 12) {
            const int r = sub & 3;
            const int m = sub >> 2;
            unsigned key = (r == 0) ? k0 : (r == 1) ? k1 : (r == 2) ? k2 : k3;
            const float conf = __uint_as_float((key >> 6) + OFFBITS);
            const int bid = bin_of(conf);
            float val;
            if (m == 0)      val = 1.0f;
            else if (m == 1) val = conf;
            else {
                const int pred = 63 - (int)(key & 63u);
                val = (pred == lab) ? 1.0f : 0.0f;     // lane 8+r holds labels[rb+r]
            }
            atomicAdd(&hrep[m * N_BINS + bid], val);
        }
    }

    // Tail: rows [nfull, n), one row per 16-lane group (never runs when R | n)
    for (long long row = nfull + (long long)blockIdx.x * 16 + grp;
         row < n; row += (long long)gridDim.x * 16)
    {
        const float4 v = *reinterpret_cast<const float4*>(sm + (row << 6) + col);
        int lab = (sub == 2) ? labels[row] : 0;
        unsigned key = row_key(v, sub);
        #pragma unroll
        for (int off = 1; off < 16; off <<= 1)
            key = umax_(key, (unsigned)__shfl_xor((int)key, off));
        commit1(hrep, key, sub, lab);
    }

    __syncthreads();
    if (tid < SEG) {
        float v = 0.f;
        #pragma unroll
        for (int r = 0; r < NREP; ++r) v += s_hist[r * SEG + tid];
        atomicAdd(&g[(blockIdx.x & (NSPREAD - 1)) * SEG + tid], v);
    }
}

__global__ void ece_final_kernel(const float* __restrict__ g, float* __restrict__ out, int n)
{
    __shared__ float s[SEG];
    const int tid = threadIdx.x;
    if (tid < SEG) {
        float v = 0.f;
        #pragma unroll
        for (int r = 0; r < NSPREAD; ++r) v += g[r * SEG + tid];
        s[tid] = v;
    }
    __syncthreads();
    if (tid == 0) {
        float total = 0.f;
        #pragma unroll
        for (int i = 0; i < N_BINS; ++i) {
            const float c = s[i];
            if (c > 0.f) {
                const float d = fmaxf(c, 1.f);
                total += fabsf(s[N_BINS + i] / d - s[2*N_BINS + i] / d) * (c / (float)n);
            }
        }
        out[0] = total;
    }
}

extern "C" void kernel_launch(void* const* d_in, const int* in_sizes, int n_in,
                              void* d_out, int out_size, void* d_ws, size_t ws_size,
                              hipStream_t stream) {
    const float* sm     = (const float*)d_in[0];
    const int*   labels = (const int*)d_in[1];
    float* out = (float*)d_out;
    float* g   = (float*)d_ws;
    const int n = in_sizes[1];   // number of rows (labels count)

    hipMemsetAsync(g, 0, NSPREAD * SEG * sizeof(float), stream);

    const int grid = 2048;       // 8 blocks/CU resident; 32 full sweep stages
    ece_partial_kernel<<<grid, 256, 0, stream>>>(sm, labels, g, n);
    ece_final_kernel<<<1, 64, 0, stream>>>(g, out, n);
}

// Round 4
// 179.181 us; speedup vs baseline: 1.3033x; 1.1119x over previous
//
#include <hip/hip_runtime.h>

#define N_BINS 15
#define NREP 8               // LDS histogram replicas (de-contention)
#define NSPREAD 32           // global-atomic contention spreading
#define SEG (3 * N_BINS)     // cnt | conf | acc per replica
#define HWORDS (NREP * SEG)  // 360 floats of LDS histogram
#define OFFBITS 0x3C800000u  // fbits of 1/64: conf in [1/64,1] -> 26-bit range

typedef float f4v __attribute__((ext_vector_type(4)));

__device__ __forceinline__ unsigned umax_(unsigned a, unsigned b) { return a > b ? a : b; }

__device__ __forceinline__ f4v ldnt(const float* p) {
    return __builtin_nontemporal_load(reinterpret_cast<const f4v*>(p));
}

// key = ((fbits-OFF)<<6) | (63-idx): unsigned max == (max val, first index).
__device__ __forceinline__ unsigned row_key(const f4v v, const int sub) {
    const int base = sub << 2;
    unsigned k0 = ((umax_(__float_as_uint(v[0]), OFFBITS) - OFFBITS) << 6) | (unsigned)(63 - base);
    unsigned k1 = ((umax_(__float_as_uint(v[1]), OFFBITS) - OFFBITS) << 6) | (unsigned)(62 - base);
    unsigned k2 = ((umax_(__float_as_uint(v[2]), OFFBITS) - OFFBITS) << 6) | (unsigned)(61 - base);
    unsigned k3 = ((umax_(__float_as_uint(v[3]), OFFBITS) - OFFBITS) << 6) | (unsigned)(60 - base);
    return umax_(umax_(k0, k1), umax_(k2, k3));
}

__device__ __forceinline__ int bin_of(float conf) {
    int bid = 0;
    #pragma unroll
    for (int j = 1; j <= N_BINS; ++j)
        bid += ((float)j / 15.0f < conf) ? 1 : 0;   // searchsorted-left - 1
    return bid > N_BINS - 1 ? N_BINS - 1 : bid;
}

// single-row commit (tail path)
__device__ __forceinline__ void commit1(float* hrep, unsigned key, int sub, int lab) {
    if (sub < 3) {
        const float m = __uint_as_float((key >> 6) + OFFBITS);
        const int bid = bin_of(m);
        float val;
        if (sub == 0)      val = 1.0f;
        else if (sub == 1) val = m;
        else {
            const int pred = 63 - (int)(key & 63u);
            val = (pred == lab) ? 1.0f : 0.0f;
        }
        atomicAdd(&hrep[sub * N_BINS + bid], val);
    }
}

__global__ __launch_bounds__(256) void ece_partial_kernel(
    const float* __restrict__ sm, const int* __restrict__ labels,
    float* __restrict__ g, int n)
{
    __shared__ float s_hist[HWORDS];
    const int tid = threadIdx.x;
    for (int i = tid; i < HWORDS; i += 256) s_hist[i] = 0.f;
    __syncthreads();

    const int sub = tid & 15;          // lane within 16-lane row group
    const int grp = tid >> 4;          // group 0..15 within block
    float* hrep = s_hist + (grp & (NREP - 1)) * SEG;
    const int col = sub << 2;

    const long long R = (long long)gridDim.x * 64;     // rows per grid stage
    const long long nfull = ((long long)n / R) * R;
    const int nstages = (int)(nfull / R);
    long long rb = (long long)blockIdx.x * 64 + ((long long)grp << 2);

    // process 4 rows held in registers -> one LDS atomic instr (12 lanes)
    auto process = [&](f4v v0, f4v v1, f4v v2, f4v v3, int lab) {
        unsigned k0 = row_key(v0, sub);
        unsigned k1 = row_key(v1, sub);
        unsigned k2 = row_key(v2, sub);
        unsigned k3 = row_key(v3, sub);
        #pragma unroll
        for (int off = 1; off < 16; off <<= 1) {       // 4 interleaved butterflies
            k0 = umax_(k0, (unsigned)__shfl_xor((int)k0, off));
            k1 = umax_(k1, (unsigned)__shfl_xor((int)k1, off));
            k2 = umax_(k2, (unsigned)__shfl_xor((int)k2, off));
            k3 = umax_(k3, (unsigned)__shfl_xor((int)k3, off));
        }
        if (sub < 12) {                                // lane sub=4*m+r owns (row r, metric m)
            const int r = sub & 3;
            const int m = sub >> 2;
            unsigned key = (r == 0) ? k0 : (r == 1) ? k1 : (r == 2) ? k2 : k3;
            const float conf = __uint_as_float((key >> 6) + OFFBITS);
            const int bid = bin_of(conf);
            float val;
            if (m == 0)      val = 1.0f;
            else if (m == 1) val = conf;
            else {
                const int pred = 63 - (int)(key & 63u);
                val = (pred == lab) ? 1.0f : 0.0f;     // lane 8+r holds labels[rb+r]
            }
            atomicAdd(&hrep[m * N_BINS + bid], val);
        }
    };

    if (nstages > 0) {
        // prologue: stage 0 loads
        f4v v0 = ldnt(sm + (rb << 6) + col);
        f4v v1 = ldnt(sm + ((rb + 1) << 6) + col);
        f4v v2 = ldnt(sm + ((rb + 2) << 6) + col);
        f4v v3 = ldnt(sm + ((rb + 3) << 6) + col);
        int lab = 0;
        if ((unsigned)(sub - 8) < 4u) lab = labels[rb + (sub & 3)];

        // steady state: prefetch stage s+1 into regs, then process stage s
        for (int s = 0; s < nstages - 1; ++s) {
            const long long nrb = rb + R;
            f4v w0 = ldnt(sm + (nrb << 6) + col);
            f4v w1 = ldnt(sm + ((nrb + 1) << 6) + col);
            f4v w2 = ldnt(sm + ((nrb + 2) << 6) + col);
            f4v w3 = ldnt(sm + ((nrb + 3) << 6) + col);
            int nlab = 0;
            if ((unsigned)(sub - 8) < 4u) nlab = labels[nrb + (sub & 3)];

            process(v0, v1, v2, v3, lab);

            v0 = w0; v1 = w1; v2 = w2; v3 = w3; lab = nlab; rb = nrb;
        }
        process(v0, v1, v2, v3, lab);                  // epilogue
    }

    // Tail: rows [nfull, n) (never runs when R | n, e.g. n = 4194304)
    for (long long row = nfull + (long long)blockIdx.x * 16 + grp;
         row < n; row += (long long)gridDim.x * 16)
    {
        const f4v v = ldnt(sm + (row << 6) + col);
        int lab = (sub == 2) ? labels[row] : 0;
        unsigned key = row_key(v, sub);
        #pragma unroll
        for (int off = 1; off < 16; off <<= 1)
            key = umax_(key, (unsigned)__shfl_xor((int)key, off));
        commit1(hrep, key, sub, lab);
    }

    __syncthreads();
    if (tid < SEG) {
        float v = 0.f;
        #pragma unroll
        for (int r = 0; r < NREP; ++r) v += s_hist[r * SEG + tid];
        atomicAdd(&g[(blockIdx.x & (NSPREAD - 1)) * SEG + tid], v);
    }
}

__global__ void ece_final_kernel(const float* __restrict__ g, float* __restrict__ out, int n)
{
    __shared__ float s[SEG];
    const int tid = threadIdx.x;
    if (tid < SEG) {
        float v = 0.f;
        #pragma unroll
        for (int r = 0; r < NSPREAD; ++r) v += g[r * SEG + tid];
        s[tid] = v;
    }
    __syncthreads();
    if (tid == 0) {
        float total = 0.f;
        #pragma unroll
        for (int i = 0; i < N_BINS; ++i) {
            const float c = s[i];
            if (c > 0.f) {
                const float d = fmaxf(c, 1.f);
                total += fabsf(s[N_BINS + i] / d - s[2*N_BINS + i] / d) * (c / (float)n);
            }
        }
        out[0] = total;
    }
}

extern "C" void kernel_launch(void* const* d_in, const int* in_sizes, int n_in,
                              void* d_out, int out_size, void* d_ws, size_t ws_size,
                              hipStream_t stream) {
    const float* sm     = (const float*)d_in[0];
    const int*   labels = (const int*)d_in[1];
    float* out = (float*)d_out;
    float* g   = (float*)d_ws;
    const int n = in_sizes[1];   // number of rows (labels count)

    hipMemsetAsync(g, 0, NSPREAD * SEG * sizeof(float), stream);

    const int grid = 2048;       // 8 blocks/CU; 32 pipelined sweep stages
    ece_partial_kernel<<<grid, 256, 0, stream>>>(sm, labels, g, n);
    ece_final_kernel<<<1, 64, 0, stream>>>(g, out, n);
}